// Round 18
// baseline (420.587 us; speedup 1.0000x reference)
//
#include <hip/hip_runtime.h>
#include <hip/hip_bf16.h>

// Two-layer RGCN (mean aggregation per relation) for MI355X.
// Round 18: r13 skeleton (best, 251.6 us) with a barrier-free LDS-free GEMM.
// Weights (294/147 KB) are L2-resident: read B-fragments straight from
// pre-transposed global Wt per MFMA. No __syncthreads, no LDS -> per-wave
// ILP hides A-load latency (the barriered version drained vmcnt every
// segment at 3 blocks/CU -> MfmaUtil 10%). Fusion abandoned (5 attempts,
// all latency-bound). agg/bucket/CSR identical to r13.

#define D_IN 128
#define NREL 8

typedef short bf16x8 __attribute__((ext_vector_type(8)));
typedef float f32x4 __attribute__((ext_vector_type(4)));

__device__ __forceinline__ ushort cvbf(float f) {  // f32 -> bf16 RNE
    unsigned u = __float_as_uint(f);
    return (ushort)((u + 0x7FFFu + ((u >> 16) & 1u)) >> 16);
}
__device__ __forceinline__ float bflo(unsigned v) { return __uint_as_float(v << 16); }
__device__ __forceinline__ float bfhi(unsigned v) { return __uint_as_float(v & 0xFFFF0000u); }

// ---------------- f32 -> bf16 convert (4 elems/thread) ----------------
__global__ void to_bf16_kernel(const float* __restrict__ in,
                               ushort* __restrict__ out, int n4) {
    int i = blockIdx.x * blockDim.x + threadIdx.x;
    if (i >= n4) return;
    float4 v = ((const float4*)in)[i];
    ushort4 o;
    o.x = cvbf(v.x); o.y = cvbf(v.y); o.z = cvbf(v.z); o.w = cvbf(v.w);
    ((ushort4*)out)[i] = o;
}

// -------- weight pre-transform: bf16 W^T (plain): Wt[s][n][k] --------------
__global__ void wt_transform_kernel(const float* __restrict__ W,
                                    const float* __restrict__ root,
                                    ushort* __restrict__ Wt, int NCOLS) {
    int i = blockIdx.x * blockDim.x + threadIdx.x;
    int tot = (NREL + 1) * D_IN * NCOLS;
    if (i >= tot) return;
    int s = i / (D_IN * NCOLS);
    int r = i - s * D_IN * NCOLS;
    int k = r / NCOLS;
    int n = r - k * NCOLS;
    float v = (s < NREL) ? W[(size_t)s * D_IN * NCOLS + (size_t)k * NCOLS + n]
                         : root[(size_t)k * NCOLS + n];
    Wt[((size_t)s * NCOLS + n) * D_IN + k] = cvbf(v);
}

// ---------------- CSR build (seg = et*N + dst, relation-major) -------------
__global__ void count_kernel(const int* __restrict__ dst,
                             const int* __restrict__ et,
                             int* __restrict__ cnt, int E, int N) {
    int e = blockIdx.x * blockDim.x + threadIdx.x;
    if (e < E) atomicAdd(&cnt[et[e] * N + dst[e]], 1);
}

__global__ void scan_block_sum(const int* __restrict__ cnt,
                               int* __restrict__ bsum, int nseg) {
    __shared__ int s[256];
    int base = blockIdx.x * 1024 + threadIdx.x * 4;
    int v = 0;
#pragma unroll
    for (int i = 0; i < 4; ++i) {
        int idx = base + i;
        if (idx < nseg) v += cnt[idx];
    }
    s[threadIdx.x] = v;
    __syncthreads();
    for (int off = 128; off > 0; off >>= 1) {
        if (threadIdx.x < off) s[threadIdx.x] += s[threadIdx.x + off];
        __syncthreads();
    }
    if (threadIdx.x == 0) bsum[blockIdx.x] = s[0];
}

__global__ void scan_bsum(int* __restrict__ bsum, int nb) {
    __shared__ int s[512];
    int t = threadIdx.x;
    int my = (t < nb) ? bsum[t] : 0;
    s[t] = my;
    __syncthreads();
    for (int off = 1; off < 512; off <<= 1) {
        int v = (t >= off) ? s[t - off] : 0;
        __syncthreads();
        s[t] += v;
        __syncthreads();
    }
    if (t < nb) bsum[t] = s[t] - my;  // exclusive
}

__global__ void scan_write(const int* __restrict__ cnt,
                           const int* __restrict__ bsum,
                           int* __restrict__ off, int nseg) {
    __shared__ int s[256];
    int t = threadIdx.x;
    int base = blockIdx.x * 1024 + t * 4;
    int v[4];
    int sum = 0;
#pragma unroll
    for (int i = 0; i < 4; ++i) {
        int idx = base + i;
        v[i] = (idx < nseg) ? cnt[idx] : 0;
        sum += v[i];
    }
    s[t] = sum;
    __syncthreads();
    int my = sum;
    for (int o = 1; o < 256; o <<= 1) {
        int x = (t >= o) ? s[t - o] : 0;
        __syncthreads();
        s[t] += x;
        __syncthreads();
    }
    int pre = s[t] - my + bsum[blockIdx.x];
#pragma unroll
    for (int i = 0; i < 4; ++i) {
        int idx = base + i;
        if (idx < nseg) {
            off[idx] = pre;
            pre += v[i];
        }
    }
}

__global__ void bucket_kernel(const int* __restrict__ src,
                              const int* __restrict__ dst,
                              const int* __restrict__ et,
                              int* __restrict__ off,
                              ushort* __restrict__ sids, int E, int N) {
    int e = blockIdx.x * blockDim.x + threadIdx.x;
    if (e < E) {
        int seg = et[e] * N + dst[e];
        int pos = atomicAdd(&off[seg], 1);
        sids[pos] = (ushort)src[e];
    }
}

// -------- atomic-free segment mean (bf16 in/out): 16-lane group / segment ---
// 4 segments per wave; lane handles 16 B (8 bf16 channels) of the 256 B row.
// sids block-loaded 16-at-a-time and broadcast via shfl (r13 exact).
__global__ __launch_bounds__(256) void aggregate_kernel(
    const ushort* __restrict__ feat,    // [N][128] bf16
    const ushort* __restrict__ sids,    // [E] src ids grouped by segment
    const int* __restrict__ endoff,     // [nseg] end offsets
    ushort* __restrict__ agg,           // [nseg][128] bf16 means
    int nseg) {
    int gid = blockIdx.x * blockDim.x + threadIdx.x;
    int s = gid >> 4;           // one segment per 16 threads
    int l = gid & 15;           // lane within group
    if (s >= nseg) return;
    int gbase = threadIdx.x & 48;  // group's base lane within the wave

    int end = endoff[s];
    int start = (s == 0) ? 0 : endoff[s - 1];
    int deg = end - start;

    float a0 = 0.f, a1 = 0.f, a2 = 0.f, a3 = 0.f;
    float a4 = 0.f, a5 = 0.f, a6 = 0.f, a7 = 0.f;
    for (int base = start; base < end; base += 16) {
        int m = min(16, end - base);
        int sid = (l < m) ? (int)sids[base + l] : 0;
#pragma unroll 2
        for (int j = 0; j < m; ++j) {
            int id = __shfl(sid, gbase + j);
            uint4 v = ((const uint4*)(feat + (size_t)id * D_IN))[l];
            a0 += bflo(v.x); a1 += bfhi(v.x);
            a2 += bflo(v.y); a3 += bfhi(v.y);
            a4 += bflo(v.z); a5 += bfhi(v.z);
            a6 += bflo(v.w); a7 += bfhi(v.w);
        }
    }
    float inv = (deg > 0) ? 1.0f / (float)deg : 0.0f;
    uint4 o;
    o.x = (unsigned)cvbf(a0 * inv) | ((unsigned)cvbf(a1 * inv) << 16);
    o.y = (unsigned)cvbf(a2 * inv) | ((unsigned)cvbf(a3 * inv) << 16);
    o.z = (unsigned)cvbf(a4 * inv) | ((unsigned)cvbf(a5 * inv) << 16);
    o.w = (unsigned)cvbf(a6 * inv) | ((unsigned)cvbf(a7 * inv) << 16);
    ((uint4*)(agg + (size_t)s * D_IN))[l] = o;
}

// ---------------- MFMA RGCN GEMM: no LDS, no barriers ----------------
// out[n][j] = bias[j] + feat[n]@root[:,j] + sum_r agg[r*N+n] @ W[r][:,j]
// B-fragments read directly from L2-resident transposed Wt.
template <int NCOLS, bool RELU, bool OUTBF16>
__global__ __launch_bounds__(256) void mfma_gemm_kernel(
    const ushort* __restrict__ feat,  // [N][128] bf16
    const ushort* __restrict__ agg,   // [R][N][128] bf16
    const ushort* __restrict__ Wt,    // [R+1][NCOLS][128] bf16 (W^T)
    const float* __restrict__ bias,   // [NCOLS]
    void* __restrict__ outp,          // [N][NCOLS] bf16 or f32
    int N) {
    constexpr int NT = NCOLS / 16;  // 16x16 col-tiles per wave

    const int tid = threadIdx.x;
    const int wave = tid >> 6;
    const int lane = tid & 63;
    const int c = lane & 15;   // A-row / D-col / B-col within tile
    const int g = lane >> 4;   // k-group
    const int rb = blockIdx.x * 64 + wave * 16;
    const int arow = min(rb + c, N - 1);
    const size_t aoff = (size_t)arow * D_IN + 8 * g;

    f32x4 acc[NT];
#pragma unroll
    for (int t = 0; t < NT; ++t) acc[t] = (f32x4){0.f, 0.f, 0.f, 0.f};

    for (int s = 0; s < NREL + 1; ++s) {
        const ushort* Aseg = (s < NREL) ? (agg + (size_t)s * N * D_IN) : feat;
        const ushort* ab = Aseg + aoff;
        bf16x8 a[4];
#pragma unroll
        for (int q = 0; q < 4; ++q) a[q] = *(const bf16x8*)(ab + 32 * q);
        const ushort* wseg = Wt + (size_t)s * NCOLS * D_IN + 8 * g;
#pragma unroll
        for (int q = 0; q < 4; ++q) {
#pragma unroll
            for (int t = 0; t < NT; ++t) {
                const ushort* bp = wseg + (size_t)(t * 16 + c) * D_IN + q * 32;
                bf16x8 b = *(const bf16x8*)bp;
                acc[t] = __builtin_amdgcn_mfma_f32_16x16x32_bf16(a[q], b, acc[t], 0, 0, 0);
            }
        }
    }

    // epilogue: D layout col=lane&15, row=(lane>>4)*4+reg
#pragma unroll
    for (int t = 0; t < NT; ++t) {
        float bv = bias[t * 16 + c];
#pragma unroll
        for (int r = 0; r < 4; ++r) {
            int orow = rb + 4 * g + r;
            if (orow < N) {
                float v = acc[t][r] + bv;
                if (RELU) v = fmaxf(v, 0.0f);
                if (OUTBF16)
                    ((ushort*)outp)[(size_t)orow * NCOLS + t * 16 + c] = cvbf(v);
                else
                    ((float*)outp)[(size_t)orow * NCOLS + t * 16 + c] = v;
            }
        }
    }
}

extern "C" void kernel_launch(void* const* d_in, const int* in_sizes, int n_in,
                              void* d_out, int out_size, void* d_ws, size_t ws_size,
                              hipStream_t stream) {
    const float* x = (const float*)d_in[0];
    const int* ei = (const int*)d_in[1];
    const int* et = (const int*)d_in[2];
    const float* W1 = (const float*)d_in[3];
    const float* root1 = (const float*)d_in[4];
    const float* bias1 = (const float*)d_in[5];
    const float* W2 = (const float*)d_in[6];
    const float* root2 = (const float*)d_in[7];
    const float* bias2 = (const float*)d_in[8];
    float* out = (float*)d_out;

    const int N = in_sizes[0] / D_IN;  // 50000
    const int E = in_sizes[2];         // 800000
    const int* src = ei;
    const int* dst = ei + E;
    const int NSEG = NREL * N;            // 400000
    const int NB = (NSEG + 1023) / 1024;  // 391 (<=512 for scan_bsum)

    // workspace layout (all 16B-aligned)
    ushort* aggb = (ushort*)d_ws;                    // NSEG*128 bf16 = 102.4 MB
    ushort* xb = aggb + (size_t)NSEG * D_IN;         // N*128 bf16    = 12.8 MB
    ushort* hb = xb + (size_t)N * D_IN;              // N*128 bf16    = 12.8 MB
    ushort* wt1 = hb + (size_t)N * D_IN;             // 9*128*128     = 0.3 MB
    ushort* wt2 = wt1 + (size_t)(NREL + 1) * D_IN * D_IN;  // 9*64*128 = 0.15 MB
    ushort* sids = wt2 + (size_t)(NREL + 1) * 64 * D_IN;   // E ushorts = 1.6 MB
    int* off = (int*)(sids + E);                     // NSEG ints
    int* cnt = off + NSEG;                           // NSEG ints
    int* bsum = cnt + NSEG;                          // NB ints

    // ---- input conversions / weight transforms (independent) ----
    to_bf16_kernel<<<(N * D_IN / 4 + 255) / 256, 256, 0, stream>>>(x, xb, N * D_IN / 4);
    wt_transform_kernel<<<((NREL + 1) * D_IN * 128 + 255) / 256, 256, 0, stream>>>(
        W1, root1, wt1, 128);
    wt_transform_kernel<<<((NREL + 1) * D_IN * 64 + 255) / 256, 256, 0, stream>>>(
        W2, root2, wt2, 64);

    // ---- CSR build (edge set identical for both layers) ----
    hipMemsetAsync(cnt, 0, (size_t)NSEG * sizeof(int), stream);
    count_kernel<<<(E + 255) / 256, 256, 0, stream>>>(dst, et, cnt, E, N);
    scan_block_sum<<<NB, 256, 0, stream>>>(cnt, bsum, NSEG);
    scan_bsum<<<1, 512, 0, stream>>>(bsum, NB);
    scan_write<<<NB, 256, 0, stream>>>(cnt, bsum, off, NSEG);
    bucket_kernel<<<(E + 255) / 256, 256, 0, stream>>>(src, dst, et, off, sids, E, N);
    // off[] now holds END offsets per segment.

    const int aggBlocks = (int)(((size_t)NSEG * 16 + 255) / 256);
    const int gemmBlocks = (N + 63) / 64;

    // ---- layer 1 ----
    aggregate_kernel<<<aggBlocks, 256, 0, stream>>>(xb, sids, off, aggb, NSEG);
    mfma_gemm_kernel<128, true, true><<<gemmBlocks, 256, 0, stream>>>(
        xb, aggb, wt1, bias1, hb, N);

    // ---- layer 2 ----
    aggregate_kernel<<<aggBlocks, 256, 0, stream>>>(hb, sids, off, aggb, NSEG);
    mfma_gemm_kernel<64, false, false><<<gemmBlocks, 256, 0, stream>>>(
        hb, aggb, wt2, bias2, out, N);
}

// Round 19
// 251.758 us; speedup vs baseline: 1.6706x; 1.6706x over previous
//
#include <hip/hip_runtime.h>
#include <hip/hip_bf16.h>

// Two-layer RGCN (mean aggregation per relation) for MI355X.
// Round 19: r13 skeleton (best, 251.6 us) + two contained changes:
//  1) prep_kernel fuses to_bf16 + both wt_transforms (3 dispatches -> 1)
//  2) gemm2 (NCOLS=64) double-buffers Bt (2x16KB, occupancy unchanged):
//     ONE barrier per segment, stage(s+1) overlaps MFMA(s).
// gemm1, aggregate, bucket, CSR identical to r13.
// History: fusion dead (5 attempts, latency-bound); global-B GEMM dead (r18,
// 3x worse); nt-store dead (r15, breaks consumer caching).

#define D_IN 128
#define NREL 8

typedef short bf16x8 __attribute__((ext_vector_type(8)));
typedef float f32x4 __attribute__((ext_vector_type(4)));

__device__ __forceinline__ ushort cvbf(float f) {  // f32 -> bf16 RNE
    unsigned u = __float_as_uint(f);
    return (ushort)((u + 0x7FFFu + ((u >> 16) & 1u)) >> 16);
}
__device__ __forceinline__ float bflo(unsigned v) { return __uint_as_float(v << 16); }
__device__ __forceinline__ float bfhi(unsigned v) { return __uint_as_float(v & 0xFFFF0000u); }

// ------- fused prep: x->bf16, W1/root1 and W2/root2 -> swizzled bf16 W^T ----
// Wt[s][n][k'] with byte-in-row = (k*2) ^ ((n&7)<<4); s==NREL is root.
__global__ void prep_kernel(const float* __restrict__ x, ushort* __restrict__ xb,
                            int n4x,
                            const float* __restrict__ W1,
                            const float* __restrict__ root1,
                            ushort* __restrict__ wt1,
                            const float* __restrict__ W2,
                            const float* __restrict__ root2,
                            ushort* __restrict__ wt2) {
    int i = blockIdx.x * blockDim.x + threadIdx.x;
    if (i < n4x) {  // x -> bf16 (4 elems/thread)
        float4 v = ((const float4*)x)[i];
        ushort4 o;
        o.x = cvbf(v.x); o.y = cvbf(v.y); o.z = cvbf(v.z); o.w = cvbf(v.w);
        ((ushort4*)xb)[i] = o;
        return;
    }
    int j = i - n4x;
    constexpr int TOT1 = (NREL + 1) * D_IN * 128;
    constexpr int TOT2 = (NREL + 1) * D_IN * 64;
    if (j < TOT1) {
        int s = j / (D_IN * 128);
        int r = j - s * (D_IN * 128);
        int k = r / 128;
        int n = r - k * 128;
        float v = (s < NREL) ? W1[(size_t)s * D_IN * 128 + (size_t)k * 128 + n]
                             : root1[(size_t)k * 128 + n];
        int byteoff = (k << 1) ^ ((n & 7) << 4);
        wt1[(size_t)s * 128 * D_IN + (size_t)n * D_IN + (byteoff >> 1)] = cvbf(v);
        return;
    }
    j -= TOT1;
    if (j < TOT2) {
        int s = j / (D_IN * 64);
        int r = j - s * (D_IN * 64);
        int k = r / 64;
        int n = r - k * 64;
        float v = (s < NREL) ? W2[(size_t)s * D_IN * 64 + (size_t)k * 64 + n]
                             : root2[(size_t)k * 64 + n];
        int byteoff = (k << 1) ^ ((n & 7) << 4);
        wt2[(size_t)s * 64 * D_IN + (size_t)n * D_IN + (byteoff >> 1)] = cvbf(v);
    }
}

// ---------------- CSR build (seg = et*N + dst, relation-major) -------------
__global__ void count_kernel(const int* __restrict__ dst,
                             const int* __restrict__ et,
                             int* __restrict__ cnt, int E, int N) {
    int e = blockIdx.x * blockDim.x + threadIdx.x;
    if (e < E) atomicAdd(&cnt[et[e] * N + dst[e]], 1);
}

__global__ void scan_block_sum(const int* __restrict__ cnt,
                               int* __restrict__ bsum, int nseg) {
    __shared__ int s[256];
    int base = blockIdx.x * 1024 + threadIdx.x * 4;
    int v = 0;
#pragma unroll
    for (int i = 0; i < 4; ++i) {
        int idx = base + i;
        if (idx < nseg) v += cnt[idx];
    }
    s[threadIdx.x] = v;
    __syncthreads();
    for (int off = 128; off > 0; off >>= 1) {
        if (threadIdx.x < off) s[threadIdx.x] += s[threadIdx.x + off];
        __syncthreads();
    }
    if (threadIdx.x == 0) bsum[blockIdx.x] = s[0];
}

__global__ void scan_bsum(int* __restrict__ bsum, int nb) {
    __shared__ int s[512];
    int t = threadIdx.x;
    int my = (t < nb) ? bsum[t] : 0;
    s[t] = my;
    __syncthreads();
    for (int off = 1; off < 512; off <<= 1) {
        int v = (t >= off) ? s[t - off] : 0;
        __syncthreads();
        s[t] += v;
        __syncthreads();
    }
    if (t < nb) bsum[t] = s[t] - my;  // exclusive
}

__global__ void scan_write(const int* __restrict__ cnt,
                           const int* __restrict__ bsum,
                           int* __restrict__ off, int nseg) {
    __shared__ int s[256];
    int t = threadIdx.x;
    int base = blockIdx.x * 1024 + t * 4;
    int v[4];
    int sum = 0;
#pragma unroll
    for (int i = 0; i < 4; ++i) {
        int idx = base + i;
        v[i] = (idx < nseg) ? cnt[idx] : 0;
        sum += v[i];
    }
    s[t] = sum;
    __syncthreads();
    int my = sum;
    for (int o = 1; o < 256; o <<= 1) {
        int x = (t >= o) ? s[t - o] : 0;
        __syncthreads();
        s[t] += x;
        __syncthreads();
    }
    int pre = s[t] - my + bsum[blockIdx.x];
#pragma unroll
    for (int i = 0; i < 4; ++i) {
        int idx = base + i;
        if (idx < nseg) {
            off[idx] = pre;
            pre += v[i];
        }
    }
}

__global__ void bucket_kernel(const int* __restrict__ src,
                              const int* __restrict__ dst,
                              const int* __restrict__ et,
                              int* __restrict__ off,
                              ushort* __restrict__ sids, int E, int N) {
    int e = blockIdx.x * blockDim.x + threadIdx.x;
    if (e < E) {
        int seg = et[e] * N + dst[e];
        int pos = atomicAdd(&off[seg], 1);
        sids[pos] = (ushort)src[e];
    }
}

// -------- atomic-free segment mean (bf16 in/out): 16-lane group / segment ---
// 4 segments per wave; lane handles 16 B (8 bf16 channels) of the 256 B row.
// sids block-loaded 16-at-a-time and broadcast via shfl (r13 exact).
__global__ __launch_bounds__(256) void aggregate_kernel(
    const ushort* __restrict__ feat,    // [N][128] bf16
    const ushort* __restrict__ sids,    // [E] src ids grouped by segment
    const int* __restrict__ endoff,     // [nseg] end offsets
    ushort* __restrict__ agg,           // [nseg][128] bf16 means
    int nseg) {
    int gid = blockIdx.x * blockDim.x + threadIdx.x;
    int s = gid >> 4;           // one segment per 16 threads
    int l = gid & 15;           // lane within group
    if (s >= nseg) return;
    int gbase = threadIdx.x & 48;  // group's base lane within the wave

    int end = endoff[s];
    int start = (s == 0) ? 0 : endoff[s - 1];
    int deg = end - start;

    float a0 = 0.f, a1 = 0.f, a2 = 0.f, a3 = 0.f;
    float a4 = 0.f, a5 = 0.f, a6 = 0.f, a7 = 0.f;
    for (int base = start; base < end; base += 16) {
        int m = min(16, end - base);
        int sid = (l < m) ? (int)sids[base + l] : 0;
#pragma unroll 2
        for (int j = 0; j < m; ++j) {
            int id = __shfl(sid, gbase + j);
            uint4 v = ((const uint4*)(feat + (size_t)id * D_IN))[l];
            a0 += bflo(v.x); a1 += bfhi(v.x);
            a2 += bflo(v.y); a3 += bfhi(v.y);
            a4 += bflo(v.z); a5 += bfhi(v.z);
            a6 += bflo(v.w); a7 += bfhi(v.w);
        }
    }
    float inv = (deg > 0) ? 1.0f / (float)deg : 0.0f;
    uint4 o;
    o.x = (unsigned)cvbf(a0 * inv) | ((unsigned)cvbf(a1 * inv) << 16);
    o.y = (unsigned)cvbf(a2 * inv) | ((unsigned)cvbf(a3 * inv) << 16);
    o.z = (unsigned)cvbf(a4 * inv) | ((unsigned)cvbf(a5 * inv) << 16);
    o.w = (unsigned)cvbf(a6 * inv) | ((unsigned)cvbf(a7 * inv) << 16);
    ((uint4*)(agg + (size_t)s * D_IN))[l] = o;
}

// ---------------- MFMA RGCN GEMM, layer 1 (r13 exact) ----------------
// out[n][j] = bias[j] + feat[n]@root[:,j] + sum_r agg[r*N+n] @ W[r][:,j]
template <int NCOLS, bool RELU, bool OUTBF16>
__global__ __launch_bounds__(256) void mfma_gemm_kernel(
    const ushort* __restrict__ feat,  // [N][128] bf16
    const ushort* __restrict__ agg,   // [R][N][128] bf16
    const ushort* __restrict__ Wt,    // [R+1][NCOLS][128] bf16 swizzled
    const float* __restrict__ bias,   // [NCOLS]
    void* __restrict__ outp,          // [N][NCOLS] bf16 or f32
    int N) {
    constexpr int NT = NCOLS / 16;  // 16x16 col-tiles per wave
    __shared__ ushort Bt[NCOLS * D_IN];

    const int tid = threadIdx.x;
    const int wave = tid >> 6;
    const int lane = tid & 63;
    const int c = lane & 15;   // A-row / D-col / B-col within tile
    const int g = lane >> 4;   // k-group
    const int rb = blockIdx.x * 64 + wave * 16;
    const int arow = min(rb + c, N - 1);

    f32x4 acc[NT];
#pragma unroll
    for (int t = 0; t < NT; ++t) acc[t] = (f32x4){0.f, 0.f, 0.f, 0.f};

    for (int s = 0; s < NREL + 1; ++s) {
        const ushort* Aseg = (s < NREL) ? (agg + (size_t)s * N * D_IN) : feat;
        {
            const uint4* srcw = (const uint4*)(Wt + (size_t)s * NCOLS * D_IN);
            uint4* dstw = (uint4*)Bt;
#pragma unroll
            for (int i = 0; i < (NCOLS * D_IN) / (8 * 256); ++i)
                dstw[tid + i * 256] = srcw[tid + i * 256];
        }
        __syncthreads();
        const ushort* Abase = Aseg + (size_t)arow * D_IN + 8 * g;
#pragma unroll
        for (int kt = 0; kt < D_IN; kt += 32) {
            bf16x8 a = *(const bf16x8*)(Abase + kt);
#pragma unroll
            for (int t = 0; t < NT; ++t) {
                int n = t * 16 + c;
                int byteoff = n * 256 + ((kt * 2 + g * 16) ^ ((n & 7) << 4));
                bf16x8 b = *(const bf16x8*)((const char*)Bt + byteoff);
                acc[t] = __builtin_amdgcn_mfma_f32_16x16x32_bf16(a, b, acc[t], 0, 0, 0);
            }
        }
        __syncthreads();
    }

#pragma unroll
    for (int t = 0; t < NT; ++t) {
        float bv = bias[t * 16 + c];
#pragma unroll
        for (int r = 0; r < 4; ++r) {
            int orow = rb + 4 * g + r;
            if (orow < N) {
                float v = acc[t][r] + bv;
                if (RELU) v = fmaxf(v, 0.0f);
                if (OUTBF16)
                    ((ushort*)outp)[(size_t)orow * NCOLS + t * 16 + c] = cvbf(v);
                else
                    ((float*)outp)[(size_t)orow * NCOLS + t * 16 + c] = v;
            }
        }
    }
}

// ------- MFMA RGCN GEMM, layer 2: double-buffered Bt, 1 barrier/segment ----
__global__ __launch_bounds__(256) void mfma_gemm_db_kernel(
    const ushort* __restrict__ feat,  // [N][128] bf16
    const ushort* __restrict__ agg,   // [R][N][128] bf16
    const ushort* __restrict__ Wt,    // [R+1][64][128] bf16 swizzled
    const float* __restrict__ bias,   // [64]
    float* __restrict__ outp,         // [N][64] f32
    int N) {
    constexpr int NCOLS = 64;
    constexpr int NT = 4;
    __shared__ ushort Bt[2][NCOLS * D_IN];  // 2 x 16 KB

    const int tid = threadIdx.x;
    const int wave = tid >> 6;
    const int lane = tid & 63;
    const int c = lane & 15;
    const int g = lane >> 4;
    const int rb = blockIdx.x * 64 + wave * 16;
    const int arow = min(rb + c, N - 1);
    const size_t aoff = (size_t)arow * D_IN + 8 * g;

#define STAGE2(S, BUF)                                                        \
    do {                                                                      \
        const uint4* srcw = (const uint4*)(Wt + (size_t)(S)*NCOLS * D_IN);    \
        uint4* dstw = (uint4*)(Bt[(BUF)]);                                    \
        _Pragma("unroll") for (int i = 0; i < (NCOLS * D_IN) / (8 * 256); ++i)\
            dstw[tid + i * 256] = srcw[tid + i * 256];                        \
    } while (0)

    f32x4 acc[NT];
#pragma unroll
    for (int t = 0; t < NT; ++t) acc[t] = (f32x4){0.f, 0.f, 0.f, 0.f};

    STAGE2(0, 0);
    __syncthreads();

    for (int s = 0; s < NREL + 1; ++s) {
        const int cur = s & 1;
        if (s < NREL) STAGE2(s + 1, cur ^ 1);  // overlaps MFMAs below
        const ushort* Aseg = (s < NREL) ? (agg + (size_t)s * N * D_IN) : feat;
        const ushort* ab = Aseg + aoff;
        const char* bt = (const char*)(Bt[cur]);
#pragma unroll
        for (int kt = 0; kt < D_IN; kt += 32) {
            bf16x8 a = *(const bf16x8*)(ab + kt);
#pragma unroll
            for (int t = 0; t < NT; ++t) {
                int n = t * 16 + c;
                int byteoff = n * 256 + ((kt * 2 + g * 16) ^ ((n & 7) << 4));
                bf16x8 b = *(const bf16x8*)(bt + byteoff);
                acc[t] = __builtin_amdgcn_mfma_f32_16x16x32_bf16(a, b, acc[t], 0, 0, 0);
            }
        }
        __syncthreads();  // stage(s+1) done; reads of Bt[cur] complete
    }

#pragma unroll
    for (int t = 0; t < NT; ++t) {
        float bv = bias[t * 16 + c];
#pragma unroll
        for (int r = 0; r < 4; ++r) {
            int orow = rb + 4 * g + r;
            if (orow < N)
                outp[(size_t)orow * NCOLS + t * 16 + c] = acc[t][r] + bv;
        }
    }
#undef STAGE2
}

extern "C" void kernel_launch(void* const* d_in, const int* in_sizes, int n_in,
                              void* d_out, int out_size, void* d_ws, size_t ws_size,
                              hipStream_t stream) {
    const float* x = (const float*)d_in[0];
    const int* ei = (const int*)d_in[1];
    const int* et = (const int*)d_in[2];
    const float* W1 = (const float*)d_in[3];
    const float* root1 = (const float*)d_in[4];
    const float* bias1 = (const float*)d_in[5];
    const float* W2 = (const float*)d_in[6];
    const float* root2 = (const float*)d_in[7];
    const float* bias2 = (const float*)d_in[8];
    float* out = (float*)d_out;

    const int N = in_sizes[0] / D_IN;  // 50000
    const int E = in_sizes[2];         // 800000
    const int* src = ei;
    const int* dst = ei + E;
    const int NSEG = NREL * N;            // 400000
    const int NB = (NSEG + 1023) / 1024;  // 391 (<=512 for scan_bsum)

    // workspace layout (all 16B-aligned)
    ushort* aggb = (ushort*)d_ws;                    // NSEG*128 bf16 = 102.4 MB
    ushort* xb = aggb + (size_t)NSEG * D_IN;         // N*128 bf16    = 12.8 MB
    ushort* hb = xb + (size_t)N * D_IN;              // N*128 bf16    = 12.8 MB
    ushort* wt1 = hb + (size_t)N * D_IN;             // 9*128*128     = 0.3 MB
    ushort* wt2 = wt1 + (size_t)(NREL + 1) * D_IN * D_IN;  // 9*64*128 = 0.15 MB
    ushort* sids = wt2 + (size_t)(NREL + 1) * 64 * D_IN;   // E ushorts = 1.6 MB
    int* off = (int*)(sids + E);                     // NSEG ints
    int* cnt = off + NSEG;                           // NSEG ints
    int* bsum = cnt + NSEG;                          // NB ints

    // ---- fused prep (x->bf16, both weight transforms) ----
    const int n4x = N * D_IN / 4;
    const int prepTot = n4x + (NREL + 1) * D_IN * 128 + (NREL + 1) * D_IN * 64;
    prep_kernel<<<(prepTot + 255) / 256, 256, 0, stream>>>(
        x, xb, n4x, W1, root1, wt1, W2, root2, wt2);

    // ---- CSR build (edge set identical for both layers) ----
    hipMemsetAsync(cnt, 0, (size_t)NSEG * sizeof(int), stream);
    count_kernel<<<(E + 255) / 256, 256, 0, stream>>>(dst, et, cnt, E, N);
    scan_block_sum<<<NB, 256, 0, stream>>>(cnt, bsum, NSEG);
    scan_bsum<<<1, 512, 0, stream>>>(bsum, NB);
    scan_write<<<NB, 256, 0, stream>>>(cnt, bsum, off, NSEG);
    bucket_kernel<<<(E + 255) / 256, 256, 0, stream>>>(src, dst, et, off, sids, E, N);
    // off[] now holds END offsets per segment.

    const int aggBlocks = (int)(((size_t)NSEG * 16 + 255) / 256);
    const int gemmBlocks = (N + 63) / 64;

    // ---- layer 1 ----
    aggregate_kernel<<<aggBlocks, 256, 0, stream>>>(xb, sids, off, aggb, NSEG);
    mfma_gemm_kernel<128, true, true><<<gemmBlocks, 256, 0, stream>>>(
        xb, aggb, wt1, bias1, hb, N);

    // ---- layer 2 ----
    aggregate_kernel<<<aggBlocks, 256, 0, stream>>>(hb, sids, off, aggb, NSEG);
    mfma_gemm_db_kernel<<<gemmBlocks, 256, 0, stream>>>(
        hb, aggb, wt2, bias2, out, N);
}

// Round 23
// 228.817 us; speedup vs baseline: 1.8381x; 1.1003x over previous
//
#include <hip/hip_runtime.h>
#include <hip/hip_bf16.h>

// Two-layer RGCN (mean aggregation per relation) for MI355X.
// Round 23 (resubmit #3 of r20; three consecutive UnresponsiveContainer infra
// failures on the same pod): replace two-pass CSR (memset+count+3 scans+
// bucket ~= 75 us; the bucket scatter alone churns 53 MB of line ping-pong)
// with single-pass LINKED-LIST bucketing: head[seg] atomicExch + coalesced
// list[e]={next,src}. aggregate walks chains (deg~2 hops; 8B uniform load
// per hop; feat load overlaps chain latency). Everything else = r19
// (251.8 us; r13-equivalent).

#define D_IN 128
#define NREL 8

typedef short bf16x8 __attribute__((ext_vector_type(8)));
typedef float f32x4 __attribute__((ext_vector_type(4)));

__device__ __forceinline__ ushort cvbf(float f) {  // f32 -> bf16 RNE
    unsigned u = __float_as_uint(f);
    return (ushort)((u + 0x7FFFu + ((u >> 16) & 1u)) >> 16);
}
__device__ __forceinline__ float bflo(unsigned v) { return __uint_as_float(v << 16); }
__device__ __forceinline__ float bfhi(unsigned v) { return __uint_as_float(v & 0xFFFF0000u); }

// ------- fused prep: x->bf16, W1/root1 and W2/root2 -> swizzled bf16 W^T ----
// Wt[s][n][k'] with byte-in-row = (k*2) ^ ((n&7)<<4); s==NREL is root.
__global__ void prep_kernel(const float* __restrict__ x, ushort* __restrict__ xb,
                            int n4x,
                            const float* __restrict__ W1,
                            const float* __restrict__ root1,
                            ushort* __restrict__ wt1,
                            const float* __restrict__ W2,
                            const float* __restrict__ root2,
                            ushort* __restrict__ wt2) {
    int i = blockIdx.x * blockDim.x + threadIdx.x;
    if (i < n4x) {  // x -> bf16 (4 elems/thread)
        float4 v = ((const float4*)x)[i];
        ushort4 o;
        o.x = cvbf(v.x); o.y = cvbf(v.y); o.z = cvbf(v.z); o.w = cvbf(v.w);
        ((ushort4*)xb)[i] = o;
        return;
    }
    int j = i - n4x;
    constexpr int TOT1 = (NREL + 1) * D_IN * 128;
    constexpr int TOT2 = (NREL + 1) * D_IN * 64;
    if (j < TOT1) {
        int s = j / (D_IN * 128);
        int r = j - s * (D_IN * 128);
        int k = r / 128;
        int n = r - k * 128;
        float v = (s < NREL) ? W1[(size_t)s * D_IN * 128 + (size_t)k * 128 + n]
                             : root1[(size_t)k * 128 + n];
        int byteoff = (k << 1) ^ ((n & 7) << 4);
        wt1[(size_t)s * 128 * D_IN + (size_t)n * D_IN + (byteoff >> 1)] = cvbf(v);
        return;
    }
    j -= TOT1;
    if (j < TOT2) {
        int s = j / (D_IN * 64);
        int r = j - s * (D_IN * 64);
        int k = r / 64;
        int n = r - k * 64;
        float v = (s < NREL) ? W2[(size_t)s * D_IN * 64 + (size_t)k * 64 + n]
                             : root2[(size_t)k * 64 + n];
        int byteoff = (k << 1) ^ ((n & 7) << 4);
        wt2[(size_t)s * 64 * D_IN + (size_t)n * D_IN + (byteoff >> 1)] = cvbf(v);
    }
}

// ---------- single-pass linked-list bucketing (seg = et*N + dst) -----------
// head[seg] = most recent edge; list[e] = {next_edge, src}. list writes are
// fully coalesced; only head (1.6 MB) sees random atomics.
__global__ void build_list_kernel(const int* __restrict__ src,
                                  const int* __restrict__ dst,
                                  const int* __restrict__ et,
                                  int* __restrict__ head,
                                  int2* __restrict__ list, int E, int N) {
    int e = blockIdx.x * blockDim.x + threadIdx.x;
    if (e < E) {
        int seg = et[e] * N + dst[e];
        int prev = atomicExch(&head[seg], e);
        list[e] = make_int2(prev, src[e]);
    }
}

// -------- atomic-free segment mean via chain walk: 16-lane group/segment ----
// All 16 lanes walk the chain together (uniform 8B load, L1 broadcast);
// the feat-row load (p.y) is independent of the next hop (p.x) -> overlaps.
__global__ __launch_bounds__(256) void aggregate_kernel(
    const ushort* __restrict__ feat,    // [N][128] bf16
    const int2* __restrict__ list,      // [E] {next, src}
    const int* __restrict__ head,       // [nseg] chain heads (-1 = empty)
    ushort* __restrict__ agg,           // [nseg][128] bf16 means
    int nseg) {
    int gid = blockIdx.x * blockDim.x + threadIdx.x;
    int s = gid >> 4;  // one segment per 16 threads
    int l = gid & 15;  // lane within group
    if (s >= nseg) return;

    int e = head[s];
    int deg = 0;
    float a0 = 0.f, a1 = 0.f, a2 = 0.f, a3 = 0.f;
    float a4 = 0.f, a5 = 0.f, a6 = 0.f, a7 = 0.f;
    while (e >= 0) {
        int2 p = list[e];  // group-uniform load
        ++deg;
        uint4 v = ((const uint4*)(feat + (size_t)p.y * D_IN))[l];
        a0 += bflo(v.x); a1 += bfhi(v.x);
        a2 += bflo(v.y); a3 += bfhi(v.y);
        a4 += bflo(v.z); a5 += bfhi(v.z);
        a6 += bflo(v.w); a7 += bfhi(v.w);
        e = p.x;
    }
    float inv = (deg > 0) ? 1.0f / (float)deg : 0.0f;
    uint4 o;
    o.x = (unsigned)cvbf(a0 * inv) | ((unsigned)cvbf(a1 * inv) << 16);
    o.y = (unsigned)cvbf(a2 * inv) | ((unsigned)cvbf(a3 * inv) << 16);
    o.z = (unsigned)cvbf(a4 * inv) | ((unsigned)cvbf(a5 * inv) << 16);
    o.w = (unsigned)cvbf(a6 * inv) | ((unsigned)cvbf(a7 * inv) << 16);
    ((uint4*)(agg + (size_t)s * D_IN))[l] = o;
}

// ---------------- MFMA RGCN GEMM, layer 1 (r13 exact) ----------------
// out[n][j] = bias[j] + feat[n]@root[:,j] + sum_r agg[r*N+n] @ W[r][:,j]
template <int NCOLS, bool RELU, bool OUTBF16>
__global__ __launch_bounds__(256) void mfma_gemm_kernel(
    const ushort* __restrict__ feat,  // [N][128] bf16
    const ushort* __restrict__ agg,   // [R][N][128] bf16
    const ushort* __restrict__ Wt,    // [R+1][NCOLS][128] bf16 swizzled
    const float* __restrict__ bias,   // [NCOLS]
    void* __restrict__ outp,          // [N][NCOLS] bf16 or f32
    int N) {
    constexpr int NT = NCOLS / 16;  // 16x16 col-tiles per wave
    __shared__ ushort Bt[NCOLS * D_IN];

    const int tid = threadIdx.x;
    const int wave = tid >> 6;
    const int lane = tid & 63;
    const int c = lane & 15;   // A-row / D-col / B-col within tile
    const int g = lane >> 4;   // k-group
    const int rb = blockIdx.x * 64 + wave * 16;
    const int arow = min(rb + c, N - 1);

    f32x4 acc[NT];
#pragma unroll
    for (int t = 0; t < NT; ++t) acc[t] = (f32x4){0.f, 0.f, 0.f, 0.f};

    for (int s = 0; s < NREL + 1; ++s) {
        const ushort* Aseg = (s < NREL) ? (agg + (size_t)s * N * D_IN) : feat;
        {
            const uint4* srcw = (const uint4*)(Wt + (size_t)s * NCOLS * D_IN);
            uint4* dstw = (uint4*)Bt;
#pragma unroll
            for (int i = 0; i < (NCOLS * D_IN) / (8 * 256); ++i)
                dstw[tid + i * 256] = srcw[tid + i * 256];
        }
        __syncthreads();
        const ushort* Abase = Aseg + (size_t)arow * D_IN + 8 * g;
#pragma unroll
        for (int kt = 0; kt < D_IN; kt += 32) {
            bf16x8 a = *(const bf16x8*)(Abase + kt);
#pragma unroll
            for (int t = 0; t < NT; ++t) {
                int n = t * 16 + c;
                int byteoff = n * 256 + ((kt * 2 + g * 16) ^ ((n & 7) << 4));
                bf16x8 b = *(const bf16x8*)((const char*)Bt + byteoff);
                acc[t] = __builtin_amdgcn_mfma_f32_16x16x32_bf16(a, b, acc[t], 0, 0, 0);
            }
        }
        __syncthreads();
    }

#pragma unroll
    for (int t = 0; t < NT; ++t) {
        float bv = bias[t * 16 + c];
#pragma unroll
        for (int r = 0; r < 4; ++r) {
            int orow = rb + 4 * g + r;
            if (orow < N) {
                float v = acc[t][r] + bv;
                if (RELU) v = fmaxf(v, 0.0f);
                if (OUTBF16)
                    ((ushort*)outp)[(size_t)orow * NCOLS + t * 16 + c] = cvbf(v);
                else
                    ((float*)outp)[(size_t)orow * NCOLS + t * 16 + c] = v;
            }
        }
    }
}

// ------- MFMA RGCN GEMM, layer 2: double-buffered Bt, 1 barrier/segment ----
__global__ void __launch_bounds__(256) mfma_gemm_db_kernel(
    const ushort* __restrict__ feat,  // [N][128] bf16
    const ushort* __restrict__ agg,   // [R][N][128] bf16
    const ushort* __restrict__ Wt,    // [R+1][64][128] bf16 swizzled
    const float* __restrict__ bias,   // [64]
    float* __restrict__ outp,         // [N][64] f32
    int N) {
    constexpr int NCOLS = 64;
    constexpr int NT = 4;
    __shared__ ushort Bt[2][NCOLS * D_IN];  // 2 x 16 KB

    const int tid = threadIdx.x;
    const int wave = tid >> 6;
    const int lane = tid & 63;
    const int c = lane & 15;
    const int g = lane >> 4;
    const int rb = blockIdx.x * 64 + wave * 16;
    const int arow = min(rb + c, N - 1);
    const size_t aoff = (size_t)arow * D_IN + 8 * g;

#define STAGE2(S, BUF)                                                        \
    do {                                                                      \
        const uint4* srcw = (const uint4*)(Wt + (size_t)(S)*NCOLS * D_IN);    \
        uint4* dstw = (uint4*)(Bt[(BUF)]);                                    \
        _Pragma("unroll") for (int i = 0; i < (NCOLS * D_IN) / (8 * 256); ++i)\
            dstw[tid + i * 256] = srcw[tid + i * 256];                        \
    } while (0)

    f32x4 acc[NT];
#pragma unroll
    for (int t = 0; t < NT; ++t) acc[t] = (f32x4){0.f, 0.f, 0.f, 0.f};

    STAGE2(0, 0);
    __syncthreads();

    for (int s = 0; s < NREL + 1; ++s) {
        const int cur = s & 1;
        if (s < NREL) STAGE2(s + 1, cur ^ 1);  // overlaps MFMAs below
        const ushort* Aseg = (s < NREL) ? (agg + (size_t)s * N * D_IN) : feat;
        const ushort* ab = Aseg + aoff;
        const char* bt = (const char*)(Bt[cur]);
#pragma unroll
        for (int kt = 0; kt < D_IN; kt += 32) {
            bf16x8 a = *(const bf16x8*)(ab + kt);
#pragma unroll
            for (int t = 0; t < NT; ++t) {
                int n = t * 16 + c;
                int byteoff = n * 256 + ((kt * 2 + g * 16) ^ ((n & 7) << 4));
                bf16x8 b = *(const bf16x8*)(bt + byteoff);
                acc[t] = __builtin_amdgcn_mfma_f32_16x16x32_bf16(a, b, acc[t], 0, 0, 0);
            }
        }
        __syncthreads();  // stage(s+1) done; reads of Bt[cur] complete
    }

#pragma unroll
    for (int t = 0; t < NT; ++t) {
        float bv = bias[t * 16 + c];
#pragma unroll
        for (int r = 0; r < 4; ++r) {
            int orow = rb + 4 * g + r;
            if (orow < N)
                outp[(size_t)orow * NCOLS + t * 16 + c] = acc[t][r] + bv;
        }
    }
#undef STAGE2
}

extern "C" void kernel_launch(void* const* d_in, const int* in_sizes, int n_in,
                              void* d_out, int out_size, void* d_ws, size_t ws_size,
                              hipStream_t stream) {
    const float* x = (const float*)d_in[0];
    const int* ei = (const int*)d_in[1];
    const int* et = (const int*)d_in[2];
    const float* W1 = (const float*)d_in[3];
    const float* root1 = (const float*)d_in[4];
    const float* bias1 = (const float*)d_in[5];
    const float* W2 = (const float*)d_in[6];
    const float* root2 = (const float*)d_in[7];
    const float* bias2 = (const float*)d_in[8];
    float* out = (float*)d_out;

    const int N = in_sizes[0] / D_IN;  // 50000
    const int E = in_sizes[2];         // 800000
    const int* src = ei;
    const int* dst = ei + E;
    const int NSEG = NREL * N;         // 400000

    // workspace layout (all 16B-aligned)
    ushort* aggb = (ushort*)d_ws;                    // NSEG*128 bf16 = 102.4 MB
    ushort* xb = aggb + (size_t)NSEG * D_IN;         // N*128 bf16    = 12.8 MB
    ushort* hb = xb + (size_t)N * D_IN;              // N*128 bf16    = 12.8 MB
    ushort* wt1 = hb + (size_t)N * D_IN;             // 9*128*128     = 0.3 MB
    ushort* wt2 = wt1 + (size_t)(NREL + 1) * D_IN * D_IN;  // 9*64*128 = 0.15 MB
    int* head = (int*)(wt2 + (size_t)(NREL + 1) * 64 * D_IN);  // NSEG ints
    int2* list = (int2*)(head + NSEG);               // E int2 = 6.4 MB

    // ---- fused prep (x->bf16, both weight transforms) ----
    const int n4x = N * D_IN / 4;
    const int prepTot = n4x + (NREL + 1) * D_IN * 128 + (NREL + 1) * D_IN * 64;
    prep_kernel<<<(prepTot + 255) / 256, 256, 0, stream>>>(
        x, xb, n4x, W1, root1, wt1, W2, root2, wt2);

    // ---- single-pass linked-list bucketing ----
    hipMemsetAsync(head, 0xFF, (size_t)NSEG * sizeof(int), stream);  // -1
    build_list_kernel<<<(E + 255) / 256, 256, 0, stream>>>(
        src, dst, et, head, list, E, N);

    const int aggBlocks = (int)(((size_t)NSEG * 16 + 255) / 256);
    const int gemmBlocks = (N + 63) / 64;

    // ---- layer 1 ----
    aggregate_kernel<<<aggBlocks, 256, 0, stream>>>(xb, list, head, aggb, NSEG);
    mfma_gemm_kernel<128, true, true><<<gemmBlocks, 256, 0, stream>>>(
        xb, aggb, wt1, bias1, hb, N);

    // ---- layer 2 ----
    aggregate_kernel<<<aggBlocks, 256, 0, stream>>>(hb, list, head, aggb, NSEG);
    mfma_gemm_db_kernel<<<gemmBlocks, 256, 0, stream>>>(
        hb, aggb, wt2, bias2, out, N);
}

// Round 24
// 225.810 us; speedup vs baseline: 1.8626x; 1.0133x over previous
//
#include <hip/hip_runtime.h>
#include <hip/hip_bf16.h>

// Two-layer RGCN (mean aggregation per relation) for MI355X.
// Round 24: r23 (228.8 us, best) + empty-segment skip (~13.5% of segments,
// e^-2 at mean deg 2):
//  - aggregate early-exits on head[s]<0 (skips 256B zero-store per empty seg)
//  - GEMMs read head (1 coalesced int/lane/segment) and zero the A-fragment
//    WITHOUT loading when empty (exec-masked lanes issue no VMEM)
// Aggregate is bandwidth-bound at ~4 TB/s (r13/r23 both), so traffic cuts
// translate ~linearly to time. Everything else identical to r23.

#define D_IN 128
#define NREL 8

typedef short bf16x8 __attribute__((ext_vector_type(8)));
typedef float f32x4 __attribute__((ext_vector_type(4)));

__device__ __forceinline__ ushort cvbf(float f) {  // f32 -> bf16 RNE
    unsigned u = __float_as_uint(f);
    return (ushort)((u + 0x7FFFu + ((u >> 16) & 1u)) >> 16);
}
__device__ __forceinline__ float bflo(unsigned v) { return __uint_as_float(v << 16); }
__device__ __forceinline__ float bfhi(unsigned v) { return __uint_as_float(v & 0xFFFF0000u); }

// ------- fused prep: x->bf16, W1/root1 and W2/root2 -> swizzled bf16 W^T ----
// Wt[s][n][k'] with byte-in-row = (k*2) ^ ((n&7)<<4); s==NREL is root.
__global__ void prep_kernel(const float* __restrict__ x, ushort* __restrict__ xb,
                            int n4x,
                            const float* __restrict__ W1,
                            const float* __restrict__ root1,
                            ushort* __restrict__ wt1,
                            const float* __restrict__ W2,
                            const float* __restrict__ root2,
                            ushort* __restrict__ wt2) {
    int i = blockIdx.x * blockDim.x + threadIdx.x;
    if (i < n4x) {  // x -> bf16 (4 elems/thread)
        float4 v = ((const float4*)x)[i];
        ushort4 o;
        o.x = cvbf(v.x); o.y = cvbf(v.y); o.z = cvbf(v.z); o.w = cvbf(v.w);
        ((ushort4*)xb)[i] = o;
        return;
    }
    int j = i - n4x;
    constexpr int TOT1 = (NREL + 1) * D_IN * 128;
    constexpr int TOT2 = (NREL + 1) * D_IN * 64;
    if (j < TOT1) {
        int s = j / (D_IN * 128);
        int r = j - s * (D_IN * 128);
        int k = r / 128;
        int n = r - k * 128;
        float v = (s < NREL) ? W1[(size_t)s * D_IN * 128 + (size_t)k * 128 + n]
                             : root1[(size_t)k * 128 + n];
        int byteoff = (k << 1) ^ ((n & 7) << 4);
        wt1[(size_t)s * 128 * D_IN + (size_t)n * D_IN + (byteoff >> 1)] = cvbf(v);
        return;
    }
    j -= TOT1;
    if (j < TOT2) {
        int s = j / (D_IN * 64);
        int r = j - s * (D_IN * 64);
        int k = r / 64;
        int n = r - k * 64;
        float v = (s < NREL) ? W2[(size_t)s * D_IN * 64 + (size_t)k * 64 + n]
                             : root2[(size_t)k * 64 + n];
        int byteoff = (k << 1) ^ ((n & 7) << 4);
        wt2[(size_t)s * 64 * D_IN + (size_t)n * D_IN + (byteoff >> 1)] = cvbf(v);
    }
}

// ---------- single-pass linked-list bucketing (seg = et*N + dst) -----------
// head[seg] = most recent edge; list[e] = {next_edge, src}. list writes are
// fully coalesced; only head (1.6 MB) sees random atomics.
__global__ void build_list_kernel(const int* __restrict__ src,
                                  const int* __restrict__ dst,
                                  const int* __restrict__ et,
                                  int* __restrict__ head,
                                  int2* __restrict__ list, int E, int N) {
    int e = blockIdx.x * blockDim.x + threadIdx.x;
    if (e < E) {
        int seg = et[e] * N + dst[e];
        int prev = atomicExch(&head[seg], e);
        list[e] = make_int2(prev, src[e]);
    }
}

// -------- atomic-free segment mean via chain walk: 16-lane group/segment ----
// All 16 lanes walk the chain together (uniform 8B load, L1 broadcast).
// Empty segments (head<0) exit WITHOUT storing; GEMMs mask them via head.
__global__ __launch_bounds__(256) void aggregate_kernel(
    const ushort* __restrict__ feat,    // [N][128] bf16
    const int2* __restrict__ list,      // [E] {next, src}
    const int* __restrict__ head,       // [nseg] chain heads (-1 = empty)
    ushort* __restrict__ agg,           // [nseg][128] bf16 means
    int nseg) {
    int gid = blockIdx.x * blockDim.x + threadIdx.x;
    int s = gid >> 4;  // one segment per 16 threads
    int l = gid & 15;  // lane within group
    if (s >= nseg) return;

    int e = head[s];
    if (e < 0) return;  // empty: no store (GEMM masks via head)
    int deg = 0;
    float a0 = 0.f, a1 = 0.f, a2 = 0.f, a3 = 0.f;
    float a4 = 0.f, a5 = 0.f, a6 = 0.f, a7 = 0.f;
    while (e >= 0) {
        int2 p = list[e];  // group-uniform load
        ++deg;
        uint4 v = ((const uint4*)(feat + (size_t)p.y * D_IN))[l];
        a0 += bflo(v.x); a1 += bfhi(v.x);
        a2 += bflo(v.y); a3 += bfhi(v.y);
        a4 += bflo(v.z); a5 += bfhi(v.z);
        a6 += bflo(v.w); a7 += bfhi(v.w);
        e = p.x;
    }
    float inv = 1.0f / (float)deg;
    uint4 o;
    o.x = (unsigned)cvbf(a0 * inv) | ((unsigned)cvbf(a1 * inv) << 16);
    o.y = (unsigned)cvbf(a2 * inv) | ((unsigned)cvbf(a3 * inv) << 16);
    o.z = (unsigned)cvbf(a4 * inv) | ((unsigned)cvbf(a5 * inv) << 16);
    o.w = (unsigned)cvbf(a6 * inv) | ((unsigned)cvbf(a7 * inv) << 16);
    ((uint4*)(agg + (size_t)s * D_IN))[l] = o;
}

// ---------------- MFMA RGCN GEMM, layer 1 (+empty-segment mask) ------------
// out[n][j] = bias[j] + feat[n]@root[:,j] + sum_r agg[r*N+n] @ W[r][:,j]
template <int NCOLS, bool RELU, bool OUTBF16>
__global__ __launch_bounds__(256) void mfma_gemm_kernel(
    const ushort* __restrict__ feat,  // [N][128] bf16
    const ushort* __restrict__ agg,   // [R][N][128] bf16
    const int* __restrict__ head,     // [R*N] chain heads (-1 = empty)
    const ushort* __restrict__ Wt,    // [R+1][NCOLS][128] bf16 swizzled
    const float* __restrict__ bias,   // [NCOLS]
    void* __restrict__ outp,          // [N][NCOLS] bf16 or f32
    int N) {
    constexpr int NT = NCOLS / 16;  // 16x16 col-tiles per wave
    __shared__ ushort Bt[NCOLS * D_IN];

    const int tid = threadIdx.x;
    const int wave = tid >> 6;
    const int lane = tid & 63;
    const int c = lane & 15;   // A-row / D-col / B-col within tile
    const int g = lane >> 4;   // k-group
    const int rb = blockIdx.x * 64 + wave * 16;
    const int arow = min(rb + c, N - 1);

    f32x4 acc[NT];
#pragma unroll
    for (int t = 0; t < NT; ++t) acc[t] = (f32x4){0.f, 0.f, 0.f, 0.f};

    for (int s = 0; s < NREL + 1; ++s) {
        const ushort* Aseg = (s < NREL) ? (agg + (size_t)s * N * D_IN) : feat;
        const bool empty = (s < NREL) && (head[(size_t)s * N + arow] < 0);
        {
            const uint4* srcw = (const uint4*)(Wt + (size_t)s * NCOLS * D_IN);
            uint4* dstw = (uint4*)Bt;
#pragma unroll
            for (int i = 0; i < (NCOLS * D_IN) / (8 * 256); ++i)
                dstw[tid + i * 256] = srcw[tid + i * 256];
        }
        __syncthreads();
        const ushort* Abase = Aseg + (size_t)arow * D_IN + 8 * g;
#pragma unroll
        for (int kt = 0; kt < D_IN; kt += 32) {
            bf16x8 a{};
            if (!empty) a = *(const bf16x8*)(Abase + kt);
#pragma unroll
            for (int t = 0; t < NT; ++t) {
                int n = t * 16 + c;
                int byteoff = n * 256 + ((kt * 2 + g * 16) ^ ((n & 7) << 4));
                bf16x8 b = *(const bf16x8*)((const char*)Bt + byteoff);
                acc[t] = __builtin_amdgcn_mfma_f32_16x16x32_bf16(a, b, acc[t], 0, 0, 0);
            }
        }
        __syncthreads();
    }

#pragma unroll
    for (int t = 0; t < NT; ++t) {
        float bv = bias[t * 16 + c];
#pragma unroll
        for (int r = 0; r < 4; ++r) {
            int orow = rb + 4 * g + r;
            if (orow < N) {
                float v = acc[t][r] + bv;
                if (RELU) v = fmaxf(v, 0.0f);
                if (OUTBF16)
                    ((ushort*)outp)[(size_t)orow * NCOLS + t * 16 + c] = cvbf(v);
                else
                    ((float*)outp)[(size_t)orow * NCOLS + t * 16 + c] = v;
            }
        }
    }
}

// --- MFMA RGCN GEMM, layer 2: double-buffered Bt + empty-segment mask ------
__global__ void __launch_bounds__(256) mfma_gemm_db_kernel(
    const ushort* __restrict__ feat,  // [N][128] bf16
    const ushort* __restrict__ agg,   // [R][N][128] bf16
    const int* __restrict__ head,     // [R*N] chain heads (-1 = empty)
    const ushort* __restrict__ Wt,    // [R+1][64][128] bf16 swizzled
    const float* __restrict__ bias,   // [64]
    float* __restrict__ outp,         // [N][64] f32
    int N) {
    constexpr int NCOLS = 64;
    constexpr int NT = 4;
    __shared__ ushort Bt[2][NCOLS * D_IN];  // 2 x 16 KB

    const int tid = threadIdx.x;
    const int wave = tid >> 6;
    const int lane = tid & 63;
    const int c = lane & 15;
    const int g = lane >> 4;
    const int rb = blockIdx.x * 64 + wave * 16;
    const int arow = min(rb + c, N - 1);
    const size_t aoff = (size_t)arow * D_IN + 8 * g;

#define STAGE2(S, BUF)                                                        \
    do {                                                                      \
        const uint4* srcw = (const uint4*)(Wt + (size_t)(S)*NCOLS * D_IN);    \
        uint4* dstw = (uint4*)(Bt[(BUF)]);                                    \
        _Pragma("unroll") for (int i = 0; i < (NCOLS * D_IN) / (8 * 256); ++i)\
            dstw[tid + i * 256] = srcw[tid + i * 256];                        \
    } while (0)

    f32x4 acc[NT];
#pragma unroll
    for (int t = 0; t < NT; ++t) acc[t] = (f32x4){0.f, 0.f, 0.f, 0.f};

    STAGE2(0, 0);
    __syncthreads();

    for (int s = 0; s < NREL + 1; ++s) {
        const int cur = s & 1;
        if (s < NREL) STAGE2(s + 1, cur ^ 1);  // overlaps MFMAs below
        const ushort* Aseg = (s < NREL) ? (agg + (size_t)s * N * D_IN) : feat;
        const bool empty = (s < NREL) && (head[(size_t)s * N + arow] < 0);
        const ushort* ab = Aseg + aoff;
        const char* bt = (const char*)(Bt[cur]);
#pragma unroll
        for (int kt = 0; kt < D_IN; kt += 32) {
            bf16x8 a{};
            if (!empty) a = *(const bf16x8*)(ab + kt);
#pragma unroll
            for (int t = 0; t < NT; ++t) {
                int n = t * 16 + c;
                int byteoff = n * 256 + ((kt * 2 + g * 16) ^ ((n & 7) << 4));
                bf16x8 b = *(const bf16x8*)(bt + byteoff);
                acc[t] = __builtin_amdgcn_mfma_f32_16x16x32_bf16(a, b, acc[t], 0, 0, 0);
            }
        }
        __syncthreads();  // stage(s+1) done; reads of Bt[cur] complete
    }

#pragma unroll
    for (int t = 0; t < NT; ++t) {
        float bv = bias[t * 16 + c];
#pragma unroll
        for (int r = 0; r < 4; ++r) {
            int orow = rb + 4 * g + r;
            if (orow < N)
                outp[(size_t)orow * NCOLS + t * 16 + c] = acc[t][r] + bv;
        }
    }
#undef STAGE2
}

extern "C" void kernel_launch(void* const* d_in, const int* in_sizes, int n_in,
                              void* d_out, int out_size, void* d_ws, size_t ws_size,
                              hipStream_t stream) {
    const float* x = (const float*)d_in[0];
    const int* ei = (const int*)d_in[1];
    const int* et = (const int*)d_in[2];
    const float* W1 = (const float*)d_in[3];
    const float* root1 = (const float*)d_in[4];
    const float* bias1 = (const float*)d_in[5];
    const float* W2 = (const float*)d_in[6];
    const float* root2 = (const float*)d_in[7];
    const float* bias2 = (const float*)d_in[8];
    float* out = (float*)d_out;

    const int N = in_sizes[0] / D_IN;  // 50000
    const int E = in_sizes[2];         // 800000
    const int* src = ei;
    const int* dst = ei + E;
    const int NSEG = NREL * N;         // 400000

    // workspace layout (all 16B-aligned)
    ushort* aggb = (ushort*)d_ws;                    // NSEG*128 bf16 = 102.4 MB
    ushort* xb = aggb + (size_t)NSEG * D_IN;         // N*128 bf16    = 12.8 MB
    ushort* hb = xb + (size_t)N * D_IN;              // N*128 bf16    = 12.8 MB
    ushort* wt1 = hb + (size_t)N * D_IN;             // 9*128*128     = 0.3 MB
    ushort* wt2 = wt1 + (size_t)(NREL + 1) * D_IN * D_IN;  // 9*64*128 = 0.15 MB
    int* head = (int*)(wt2 + (size_t)(NREL + 1) * 64 * D_IN);  // NSEG ints
    int2* list = (int2*)(head + NSEG);               // E int2 = 6.4 MB

    // ---- fused prep (x->bf16, both weight transforms) ----
    const int n4x = N * D_IN / 4;
    const int prepTot = n4x + (NREL + 1) * D_IN * 128 + (NREL + 1) * D_IN * 64;
    prep_kernel<<<(prepTot + 255) / 256, 256, 0, stream>>>(
        x, xb, n4x, W1, root1, wt1, W2, root2, wt2);

    // ---- single-pass linked-list bucketing ----
    hipMemsetAsync(head, 0xFF, (size_t)NSEG * sizeof(int), stream);  // -1
    build_list_kernel<<<(E + 255) / 256, 256, 0, stream>>>(
        src, dst, et, head, list, E, N);

    const int aggBlocks = (int)(((size_t)NSEG * 16 + 255) / 256);
    const int gemmBlocks = (N + 63) / 64;

    // ---- layer 1 ----
    aggregate_kernel<<<aggBlocks, 256, 0, stream>>>(xb, list, head, aggb, NSEG);
    mfma_gemm_kernel<128, true, true><<<gemmBlocks, 256, 0, stream>>>(
        xb, aggb, head, wt1, bias1, hb, N);

    // ---- layer 2 ----
    aggregate_kernel<<<aggBlocks, 256, 0, stream>>>(hb, list, head, aggb, NSEG);
    mfma_gemm_db_kernel<<<gemmBlocks, 256, 0, stream>>>(
        hb, aggb, head, wt2, bias2, out, N);
}